// Round 10
// baseline (109.401 us; speedup 1.0000x reference)
//
#include <hip/hip_runtime.h>

typedef float v2f __attribute__((ext_vector_type(2)));
typedef float v4f __attribute__((ext_vector_type(4)));

#define KS     11
#define HWDIM  512
#define IMG    (HWDIM*HWDIM)
#define TH     16
#define STRIPS 32              // 512 / TH
#define PLANES 96              // 32 images * 3 channels
#define EG2    2               // guard entries per side (each = 4 cols >= 5 halo w/ neighbor)
#define QW     132             // EG2 + 128 + EG2
#define NPARTIAL (PLANES*STRIPS)   // 3072

__device__ __forceinline__ float ssim_px(float mu_u, float mu_v, float Su, float Sv)
{
    const float C1v = 1e-4f, C2v = 9e-4f, EPSV = 1e-8f;
    const float uu = mu_u*mu_u, vv = mu_v*mu_v;
    const float mu2d = 0.5f*(uu - vv);   // 2 mux muy
    const float mu2s = 0.5f*(uu + vv);   // mux^2 + muy^2
    const float Sd   = 0.5f*(Su - Sv);   // 2 conv(p't')
    const float Ss   = 0.5f*(Su + Sv);   // conv(p'^2)+conv(t'^2)
    const float A  = mu2d + C1v;
    const float B  = Sd - mu2d + C2v;
    const float Cc = mu2s + C1v;
    const float D  = Ss - mu2s + C2v;
    // den > 1e-8 always; v_rcp_f32 rel err ~1e-7 << 1.7e-4 threshold
    return A * B * __builtin_amdgcn_rcpf(Cc*D + EPSV);
}

// load input row Y, cols 4t..4t+3 (one float4 each from pred/target);
// per col: u = p'+t', v = p'-t' packed as v2f (zero outside image)
#define LOADUV(Y, A, B, C, D) do {                                            \
    if ((unsigned)(Y) < HWDIM) {                                              \
        const v4f p4 = *(const v4f*)(pR + (size_t)(Y)*HWDIM);                 \
        const v4f t4 = *(const v4f*)(tR + (size_t)(Y)*HWDIM);                 \
        A = (v2f){0.5f*(p4.x + t4.x) + 1.0f, 0.5f*(p4.x - t4.x)};             \
        B = (v2f){0.5f*(p4.y + t4.y) + 1.0f, 0.5f*(p4.y - t4.y)};             \
        C = (v2f){0.5f*(p4.z + t4.z) + 1.0f, 0.5f*(p4.z - t4.z)};             \
        D = (v2f){0.5f*(p4.w + t4.w) + 1.0f, 0.5f*(p4.w - t4.w)};             \
    } else { A=(v2f)(0.f); B=(v2f)(0.f); C=(v2f)(0.f); D=(v2f)(0.f); }        \
} while(0)

// one vertical tap from ring slot S, 4 columns, packed (u,v) chains
#define VTAP(W, S) do {                                                       \
    v2f t_;                                                                   \
    t_ = (W)*A##S; mA += t_; SA = __builtin_elementwise_fma(t_, A##S, SA);    \
    t_ = (W)*B##S; mB += t_; SB = __builtin_elementwise_fma(t_, B##S, SB);    \
    t_ = (W)*C##S; mC += t_; SC = __builtin_elementwise_fma(t_, C##S, SC);    \
    t_ = (W)*D##S; mD += t_; SD = __builtin_elementwise_fma(t_, D##S, SD);    \
} while(0)

// one horizontal tap: 4-field packed fma (2x v_pk_fma_f32)
#define HF(ACC, W, T)                                                         \
    ACC = __builtin_elementwise_fma((v4f){(W),(W),(W),(W)}, (T), ACC)

__global__ __launch_bounds__(128) void ssim_stream_kernel(
    const float* __restrict__ pred,
    const float* __restrict__ target,
    const float* __restrict__ kern,
    float* __restrict__ partial)
{
    // quad-parity split: col c -> Pq[row&1][c%4][EG2 + c/4]; entry=(mu,mv,Su,Sv)
    __shared__ v4f Pq[2][4][QW];   // 16.9 KB
    __shared__ float red[2];

    const int tid   = threadIdx.x;     // 0..127; owns cols 4tid..4tid+3
    const int strip = blockIdx.x;      // 0..31
    const int plane = blockIdx.y;      // 0..95
    const int y0    = strip * TH;

    // exact 1D factors: a_j = k2d[5][j] / sqrt(k2d[5][5]); uniform -> SGPRs
    const float inv_a5 = 1.0f / sqrtf(kern[60]);
    const float w0  = kern[55]*inv_a5,  w1 = kern[56]*inv_a5;
    const float w2  = kern[57]*inv_a5,  w3 = kern[58]*inv_a5;
    const float w4  = kern[59]*inv_a5,  w5 = kern[60]*inv_a5;
    const float w6  = kern[61]*inv_a5,  w7 = kern[62]*inv_a5;
    const float w8  = kern[63]*inv_a5,  w9 = kern[64]*inv_a5;
    const float w10 = kern[65]*inv_a5;

    const float* pR = pred   + (size_t)plane * IMG + 4*tid;
    const float* tR = target + (size_t)plane * IMG + 4*tid;

    // zero guard entries (cols <0 and >=512), both row-parities, all col-parities
    if (tid < EG2) {
        const v4f z = (v4f)(0.f);
        #pragma unroll
        for (int par = 0; par < 2; ++par)
            #pragma unroll
            for (int k = 0; k < 4; ++k) {
                Pq[par][k][tid] = z;
                Pq[par][k][EG2 + 128 + tid] = z;
            }
    }

    // vertical shift-ring: 11 slots x (u,v) x 4 cols — named v2f only
    v2f A0,A1,A2,A3,A4,A5,A6,A7,A8,A9,A10;
    v2f B0,B1,B2,B3,B4,B5,B6,B7,B8,B9,B10;
    v2f C0,C1,C2,C3,C4,C5,C6,C7,C8,C9,C10;
    v2f D0,D1,D2,D3,D4,D5,D6,D7,D8,D9,D10;
    v2f nA, nB, nC, nD;

    // entering iteration r=0: slots 1..10 hold rows y0-5..y0+4, prefetch y0+5
    A0=(v2f)(0.f); B0=(v2f)(0.f); C0=(v2f)(0.f); D0=(v2f)(0.f);
    LOADUV(y0-5, A1, B1, C1, D1);
    LOADUV(y0-4, A2, B2, C2, D2);
    LOADUV(y0-3, A3, B3, C3, D3);
    LOADUV(y0-2, A4, B4, C4, D4);
    LOADUV(y0-1, A5, B5, C5, D5);
    LOADUV(y0+0, A6, B6, C6, D6);
    LOADUV(y0+1, A7, B7, C7, D7);
    LOADUV(y0+2, A8, B8, C8, D8);
    LOADUV(y0+3, A9, B9, C9, D9);
    LOADUV(y0+4, A10, B10, C10, D10);
    LOADUV(y0+5, nA, nB, nC, nD);

    float lsum = 0.f;
    for (int r = 0; r < TH; ++r) {
        // shift ring down one row
        A0=A1; B0=B1; C0=C1; D0=D1;
        A1=A2; B1=B2; C1=C2; D1=D2;
        A2=A3; B2=B3; C2=C3; D2=D3;
        A3=A4; B3=B4; C3=C4; D3=D4;
        A4=A5; B4=B5; C4=C5; D4=D5;
        A5=A6; B5=B6; C5=C6; D5=D6;
        A6=A7; B6=B7; C6=C7; D6=D7;
        A7=A8; B7=B8; C7=C8; D7=D8;
        A8=A9; B8=B9; C8=C9; D8=D9;
        A9=A10; B9=B10; C9=C10; D9=D10;
        A10=nA; B10=nB; C10=nC; D10=nD;
        // prefetch next input row (consumed next iteration)
        LOADUV(y0 + r + 6, nA, nB, nC, nD);

        // vertical 11-tap conv, packed: m*=(mu,mv), S*=(Su,Sv) per col
        v2f mA=(v2f)(0.f), SA=(v2f)(0.f), mB=(v2f)(0.f), SB=(v2f)(0.f);
        v2f mC=(v2f)(0.f), SC=(v2f)(0.f), mD=(v2f)(0.f), SD=(v2f)(0.f);
        VTAP(w0,0);  VTAP(w1,1);  VTAP(w2,2);  VTAP(w3,3);  VTAP(w4,4);
        VTAP(w5,5);  VTAP(w6,6);  VTAP(w7,7);  VTAP(w8,8);  VTAP(w9,9);
        VTAP(w10,10);

        v4f (*P)[QW] = Pq[r & 1];
        P[0][EG2 + tid] = (v4f){mA.x, mA.y, SA.x, SA.y};
        P[1][EG2 + tid] = (v4f){mB.x, mB.y, SB.x, SB.y};
        P[2][EG2 + tid] = (v4f){mC.x, mC.y, SC.x, SC.y};
        P[3][EG2 + tid] = (v4f){mD.x, mD.y, SD.x, SD.y};
        __syncthreads();

        // horizontal 11-tap conv: one 14-entry window feeds 4 output cols.
        // window entry P[k][t+m] = col 4(t+m)+k = rel offset o=4m+k; output col
        // j (0..3) takes taps o in [j-5, j+5] with weight w[o-j+5].
        v4f ac0=(v4f)(0.f), ac1=(v4f)(0.f), ac2=(v4f)(0.f), ac3=(v4f)(0.f);
        {
            v4f q;
            q = P[3][EG2+tid-2]; HF(ac0,w0,q);
            q = P[0][EG2+tid-1]; HF(ac0,w1,q); HF(ac1,w0,q);
            q = P[1][EG2+tid-1]; HF(ac0,w2,q); HF(ac1,w1,q); HF(ac2,w0,q);
            q = P[2][EG2+tid-1]; HF(ac0,w3,q); HF(ac1,w2,q); HF(ac2,w1,q); HF(ac3,w0,q);
            q = P[3][EG2+tid-1]; HF(ac0,w4,q); HF(ac1,w3,q); HF(ac2,w2,q); HF(ac3,w1,q);
            q = P[0][EG2+tid  ]; HF(ac0,w5,q); HF(ac1,w4,q); HF(ac2,w3,q); HF(ac3,w2,q);
            q = P[1][EG2+tid  ]; HF(ac0,w6,q); HF(ac1,w5,q); HF(ac2,w4,q); HF(ac3,w3,q);
            q = P[2][EG2+tid  ]; HF(ac0,w7,q); HF(ac1,w6,q); HF(ac2,w5,q); HF(ac3,w4,q);
            q = P[3][EG2+tid  ]; HF(ac0,w8,q); HF(ac1,w7,q); HF(ac2,w6,q); HF(ac3,w5,q);
            q = P[0][EG2+tid+1]; HF(ac0,w9,q); HF(ac1,w8,q); HF(ac2,w7,q); HF(ac3,w6,q);
            q = P[1][EG2+tid+1]; HF(ac0,w10,q);HF(ac1,w9,q); HF(ac2,w8,q); HF(ac3,w7,q);
            q = P[2][EG2+tid+1];               HF(ac1,w10,q);HF(ac2,w9,q); HF(ac3,w8,q);
            q = P[3][EG2+tid+1];                             HF(ac2,w10,q);HF(ac3,w9,q);
            q = P[0][EG2+tid+2];                                           HF(ac3,w10,q);
        }
        lsum += ssim_px(ac0.x, ac0.y, ac0.z, ac0.w);
        lsum += ssim_px(ac1.x, ac1.y, ac1.z, ac1.w);
        lsum += ssim_px(ac2.x, ac2.y, ac2.z, ac2.w);
        lsum += ssim_px(ac3.x, ac3.y, ac3.z, ac3.w);
        // no trailing barrier: parity reuse at r+2 is ordered by barrier r+1
    }

    // deterministic block reduction (2 waves)
    #pragma unroll
    for (int off = 32; off > 0; off >>= 1)
        lsum += __shfl_down(lsum, off, 64);
    if ((tid & 63) == 0) red[tid >> 6] = lsum;
    __syncthreads();
    if (tid == 0)
        partial[plane * STRIPS + strip] = red[0] + red[1];
}

__global__ __launch_bounds__(64) void ssim_reduce_kernel(
    const float* __restrict__ partial,
    float* __restrict__ out)
{
    const int b    = blockIdx.x;    // image 0..31
    const int lane = threadIdx.x;   // 0..63
    // image b owns partials [96b, 96b+96): planes 3b..3b+2, 32 strips each
    float s = partial[b * 96 + lane];
    if (lane < 32) s += partial[b * 96 + 64 + lane];
    #pragma unroll
    for (int off = 32; off > 0; off >>= 1)
        s += __shfl_down(s, off, 64);
    if (lane == 0) out[b] = s * (1.0f / (3.0f * 512.0f * 512.0f));
}

extern "C" void kernel_launch(void* const* d_in, const int* in_sizes, int n_in,
                              void* d_out, int out_size, void* d_ws, size_t ws_size,
                              hipStream_t stream) {
    (void)in_sizes; (void)n_in; (void)out_size; (void)ws_size;
    const float* pred   = (const float*)d_in[0];
    const float* target = (const float*)d_in[1];
    const float* kern   = (const float*)d_in[2];
    float* out     = (float*)d_out;
    float* partial = (float*)d_ws;   // NPARTIAL * 4 = 12288 bytes

    dim3 grid(STRIPS, PLANES);
    ssim_stream_kernel<<<grid, 128, 0, stream>>>(pred, target, kern, partial);
    ssim_reduce_kernel<<<32, 64, 0, stream>>>(partial, out);
}